// Round 2
// baseline (1302.180 us; speedup 1.0000x reference)
//
#include <hip/hip_runtime.h>
#include <cmath>

#define B_     8
#define CI_    3
#define CM_    21
#define H_     128
#define W_     128
#define K_     32
#define PAD_   8
#define PW_    144
#define PH_    144
#define NC_    3      // mask channels per block (21 = 7 groups of 3)
#define TR_    16     // tile rows per block
#define LROWS_ 24     // staged LDS rows = TR_ + 2*4 (d<=4 halo)
#define LQ_    36     // f4 per padded row (144/4)

typedef float f4 __attribute__((ext_vector_type(4)));
typedef f4 __attribute__((aligned(4))) f4u;

// 3x3 neighborhood minus center, row-major
constexpr int OI[8] = {-1,-1,-1, 0, 0, 1, 1, 1};
constexpr int OJ[8] = {-1, 0, 1,-1, 1,-1, 0, 1};

struct PosSoft { float v[K_]; };

// shifted window: elements [S .. S+3] of concat(A,B)
template<int S>
__device__ __forceinline__ f4 shw(f4 A, f4 B) {
  if constexpr (S == 0) return A;
  else if constexpr (S == 1) return (f4){A.y, A.z, A.w, B.x};
  else if constexpr (S == 2) return (f4){A.z, A.w, B.x, B.y};
  else                       return (f4){A.w, B.x, B.y, B.z};
}

// ---------------------------------------------------------------------------
// Phase A: per-pixel affinity (softmax over K=32) + constant position term.
// ---------------------------------------------------------------------------
__global__ __launch_bounds__(128) void aff_kernel(const float* __restrict__ imgs,
                                                  float* __restrict__ aff,
                                                  PosSoft ps) {
  const int j = threadIdx.x;
  const int i = blockIdx.x;
  const int b = blockIdx.y;
  const float* img = imgs + (size_t)b * CI_ * H_ * W_;

  float ctr[CI_];
#pragma unroll
  for (int c = 0; c < CI_; ++c) ctr[c] = img[c * H_ * W_ + i * W_ + j];

  float s[CI_] = {0.f, 0.f, 0.f}, s2[CI_] = {0.f, 0.f, 0.f};
#pragma unroll
  for (int k = 0; k < K_; ++k) {
    const int d  = 1 << (k >> 3);
    const int ci = min(max(i + OI[k & 7] * d, 0), H_ - 1);
    const int cj = min(max(j + OJ[k & 7] * d, 0), W_ - 1);
#pragma unroll
    for (int c = 0; c < CI_; ++c) {
      float v = img[c * H_ * W_ + ci * W_ + cj];
      s[c] += v; s2[c] += v * v;
    }
  }

  float inv[CI_];
#pragma unroll
  for (int c = 0; c < CI_; ++c) {
    float mean = s[c] * (1.f / K_);
    float var  = (s2[c] - (float)K_ * mean * mean) * (1.f / (K_ - 1));
    var = fmaxf(var, 0.f);
    inv[c] = 1.f / ((sqrtf(var) + 1e-8f) * 0.3f);
  }

  float araw[K_];
#pragma unroll
  for (int k = 0; k < K_; ++k) {
    const int d  = 1 << (k >> 3);
    const int ci = min(max(i + OI[k & 7] * d, 0), H_ - 1);
    const int cj = min(max(j + OJ[k & 7] * d, 0), W_ - 1);
    float t = 0.f;
#pragma unroll
    for (int c = 0; c < CI_; ++c) {
      float v  = img[c * H_ * W_ + ci * W_ + cj];
      float dd = fabsf(v - ctr[c]) * inv[c];
      t += dd * dd;
    }
    araw[k] = -t * (1.f / CI_);
  }

  float m = araw[0];
#pragma unroll
  for (int k = 1; k < K_; ++k) m = fmaxf(m, araw[k]);
  float sum = 0.f;
#pragma unroll
  for (int k = 0; k < K_; ++k) { float e = __expf(araw[k] - m); araw[k] = e; sum += e; }
  const float rs = 1.f / sum;

  float* ap = aff + ((size_t)b * K_) * (H_ * W_) + i * W_ + j;
#pragma unroll
  for (int k = 0; k < K_; ++k) ap[(size_t)k * (H_ * W_)] = araw[k] * rs + ps.v[k];
}

// ---------------------------------------------------------------------------
// Pad masks into edge-replicated 144x144 planes.
// ---------------------------------------------------------------------------
__global__ void pad_kernel(const float* __restrict__ src, float* __restrict__ dst,
                           int total) {
  int idx = blockIdx.x * blockDim.x + threadIdx.x;
  if (idx >= total) return;
  int pj = idx % PW_;
  int t  = idx / PW_;
  int pi = t % PH_;
  int p  = t / PH_;
  int i = min(max(pi - PAD_, 0), H_ - 1);
  int j = min(max(pj - PAD_, 0), W_ - 1);
  dst[idx] = src[(size_t)p * (H_ * W_) + i * W_ + j];
}

// ---- vertical+diagonal taps for dilation D (1,2,4) from LDS ---------------
template<int D, int DD>
__device__ __forceinline__ void vert_lds(const f4* __restrict__ lds,
                                         const f4* __restrict__ ap4, int KS,
                                         int tr, int q0, f4* acc) {
  constexpr int S  = D & 3;            // 1,2,0
  constexpr int SM = (4 - S) & 3;      // 3,2,0
  constexpr int K0 = DD * 8;
  f4 au0 = ap4[(K0 + 0) * KS], au1 = ap4[(K0 + 1) * KS], au2 = ap4[(K0 + 2) * KS];
  f4 ad0 = ap4[(K0 + 5) * KS], ad1 = ap4[(K0 + 6) * KS], ad2 = ap4[(K0 + 7) * KS];
#pragma unroll
  for (int c = 0; c < NC_; ++c) {
    const f4* RU = lds + c * (LROWS_ * LQ_) + (tr + 4 - D) * LQ_;
    const f4* RD = lds + c * (LROWS_ * LQ_) + (tr + 4 + D) * LQ_;
    f4 ua = RU[q0 - 1], ub = RU[q0], uc = RU[q0 + 1];
    f4 da = RD[q0 - 1], db = RD[q0], dc = RD[q0 + 1];
    if constexpr (S == 0) {
      acc[c] += au0 * ua + au1 * ub + au2 * uc;
      acc[c] += ad0 * da + ad1 * db + ad2 * dc;
    } else {
      acc[c] += au0 * shw<SM>(ua, ub) + au1 * ub + au2 * shw<S>(ub, uc);
      acc[c] += ad0 * shw<SM>(da, db) + ad1 * db + ad2 * shw<S>(db, dc);
    }
  }
}

// ---- vertical+diagonal taps for dilation 8 straight from global (aligned) -
__device__ __forceinline__ void vert_g8(const float* __restrict__ plane0,
                                        const f4* __restrict__ ap4, int KS,
                                        int i0, int tr, int qx, f4* acc) {
  constexpr int K0 = 24;
  f4 au0 = ap4[(K0 + 0) * KS], au1 = ap4[(K0 + 1) * KS], au2 = ap4[(K0 + 2) * KS];
  f4 ad0 = ap4[(K0 + 5) * KS], ad1 = ap4[(K0 + 6) * KS], ad2 = ap4[(K0 + 7) * KS];
#pragma unroll
  for (int c = 0; c < NC_; ++c) {
    const f4* G  = reinterpret_cast<const f4*>(plane0 + (size_t)c * (PH_ * PW_));
    const f4* GU = G + (size_t)(i0 + tr) * LQ_;        // padded row i+8-8
    const f4* GD = G + (size_t)(i0 + tr + 16) * LQ_;   // padded row i+8+8
    acc[c] += au0 * GU[qx] + au1 * GU[qx + 2] + au2 * GU[qx + 4];
    acc[c] += ad0 * GD[qx] + ad1 * GD[qx + 2] + ad2 * GD[qx + 4];
  }
}

// ---------------------------------------------------------------------------
// Propagation step, LDS-staged. Block = 512 thr = tile 16 rows x 128 cols,
// 3 channels. Grid = 448 blocks, XCD-swizzled (b = bid & 7).
// ---------------------------------------------------------------------------
template <int PADOUT>
__global__ __launch_bounds__(512, 4) void iter_kernel(const float* __restrict__ src,
                                                      const float* __restrict__ aff,
                                                      float* __restrict__ dst) {
  __shared__ f4 lds[NC_ * LROWS_ * LQ_];   // 41472 B

  const int bid  = blockIdx.x;
  const int b    = bid & 7;          // XCD-locality: batch -> XCD
  const int rest = bid >> 3;
  const int tile = rest & 7;         // 8 row tiles
  const int grp  = rest >> 3;        // 7 channel groups

  const int tid = threadIdx.x;
  const int qx  = tid & 31;          // col quad 0..31
  const int tr  = tid >> 5;          // row in tile 0..15
  const int i0  = tile * TR_;
  const int c0  = grp * NC_;

  const float* plane0 = src + ((size_t)(b * CM_ + c0)) * (PH_ * PW_);

  // ---- stage padded rows [i0+4, i0+28) x 144 cols x 3 channels (contiguous)
  {
    const f4* s4 = reinterpret_cast<const f4*>(plane0 + (size_t)(i0 + 4) * PW_);
    const int CH4 = PH_ * PW_ / 4;
    const int NSLOT = NC_ * LROWS_ * LQ_;     // 2592
    for (int s = tid; s < NSLOT; s += 512) {
      int c  = s / (LROWS_ * LQ_);
      int rq = s - c * (LROWS_ * LQ_);
      lds[s] = s4[(size_t)c * CH4 + rq];
    }
  }
  __syncthreads();

  const int q0 = qx + 2;
  const int i  = i0 + tr;
  const int j0 = qx * 4;

  const int KS = (H_ * W_) / 4;
  const f4* ap4 = reinterpret_cast<const f4*>(aff) + (size_t)b * K_ * KS + i * (W_ / 4) + qx;

  f4 acc[NC_];
#pragma unroll
  for (int c = 0; c < NC_; ++c) acc[c] = (f4){0.f, 0.f, 0.f, 0.f};

  // ---- horizontal taps (0,+-d) for all dilations: row i, 5 aligned f4/ch
  {
    f4 a1m = ap4[ 3 * KS], a1p = ap4[ 4 * KS];
    f4 a2m = ap4[11 * KS], a2p = ap4[12 * KS];
    f4 a4m = ap4[19 * KS], a4p = ap4[20 * KS];
    f4 a8m = ap4[27 * KS], a8p = ap4[28 * KS];
#pragma unroll
    for (int c = 0; c < NC_; ++c) {
      const f4* RM = lds + c * (LROWS_ * LQ_) + (tr + 4) * LQ_;
      f4 m_2 = RM[q0 - 2], m_1 = RM[q0 - 1], m0 = RM[q0], m1 = RM[q0 + 1], m2 = RM[q0 + 2];
      acc[c] += a1m * shw<3>(m_1, m0) + a1p * shw<1>(m0, m1);
      acc[c] += a2m * shw<2>(m_1, m0) + a2p * shw<2>(m0, m1);
      acc[c] += a4m * m_1 + a4p * m1;
      acc[c] += a8m * m_2 + a8p * m2;
    }
  }

  // ---- vertical + diagonal taps
  vert_lds<1, 0>(lds, ap4, KS, tr, q0, acc);
  vert_lds<2, 1>(lds, ap4, KS, tr, q0, acc);
  vert_lds<4, 2>(lds, ap4, KS, tr, q0, acc);
  vert_g8(plane0, ap4, KS, i0, tr, qx, acc);

  // ---- epilogue
  if (PADOUT) {
    const int pr = i + PAD_;
    const int r0 = (i == 0)      ? 0         : pr;
    const int r1 = (i == H_ - 1) ? (PH_ - 1) : pr;
#pragma unroll
    for (int c = 0; c < NC_; ++c) {
      float* dc = dst + ((size_t)(b * CM_ + c0 + c)) * (PH_ * PW_);
      for (int r = r0; r <= r1; ++r) {
        float* row = dc + r * PW_;
        *reinterpret_cast<f4*>(row + PAD_ + j0) = acc[c];
        if (qx == 0) {
          f4 sp = (f4){acc[c].x, acc[c].x, acc[c].x, acc[c].x};
          *reinterpret_cast<f4*>(row)     = sp;
          *reinterpret_cast<f4*>(row + 4) = sp;
        }
        if (qx == 31) {
          f4 sp = (f4){acc[c].w, acc[c].w, acc[c].w, acc[c].w};
          *reinterpret_cast<f4*>(row + PW_ - 8) = sp;
          *reinterpret_cast<f4*>(row + PW_ - 4) = sp;
        }
      }
    }
  } else {
    float* dc = dst + ((size_t)(b * CM_ + c0)) * (H_ * W_) + (size_t)i * W_ + j0;
#pragma unroll
    for (int c = 0; c < NC_; ++c) {
      *reinterpret_cast<f4*>(dc + (size_t)c * (H_ * W_)) = acc[c];
    }
  }
}

// ---------------------------------------------------------------------------
extern "C" void kernel_launch(void* const* d_in, const int* in_sizes, int n_in,
                              void* d_out, int out_size, void* d_ws, size_t ws_size,
                              hipStream_t stream) {
  const float* imgs  = (const float*)d_in[0];
  const float* masks = (const float*)d_in[1];
  float* out = (float*)d_out;

  char* ws = (char*)d_ws;
  const size_t affBytes = (size_t)B_ * K_ * H_ * W_ * sizeof(float);
  const size_t padBytes = (size_t)B_ * CM_ * PH_ * PW_ * sizeof(float);
  float* aff = (float*)ws;
  float* P0  = (float*)(ws + affBytes);
  float* P1  = (float*)(ws + affBytes + padBytes);

  PosSoft ps;
  {
    const double pv[8] = {1.4142135623730951, 1.0, 1.4142135623730951, 1.0,
                          1.0, 1.4142135623730951, 1.0, 1.4142135623730951};
    double pos[K_];
    for (int di = 0; di < 4; ++di) {
      double d = (double)(1 << di);
      for (int o = 0; o < 8; ++o) pos[di * 8 + o] = pv[o] * d;
    }
    double mean = 0; for (int k = 0; k < K_; ++k) mean += pos[k]; mean /= K_;
    double var = 0;  for (int k = 0; k < K_; ++k) { double dd = pos[k] - mean; var += dd * dd; }
    var /= (K_ - 1);
    double sd = sqrt(var);
    double pa[K_]; double m = -1e300;
    for (int k = 0; k < K_; ++k) {
      double r = pos[k] / ((sd + 1e-8) * 0.3);
      pa[k] = -(r * r);
      if (pa[k] > m) m = pa[k];
    }
    double es = 0; for (int k = 0; k < K_; ++k) { pa[k] = exp(pa[k] - m); es += pa[k]; }
    for (int k = 0; k < K_; ++k) ps.v[k] = (float)(0.01 * pa[k] / es);
  }

  aff_kernel<<<dim3(H_, B_), 128, 0, stream>>>(imgs, aff, ps);

  const int total = B_ * CM_ * PH_ * PW_;
  pad_kernel<<<(total + 255) / 256, 256, 0, stream>>>(masks, P0, total);

  const int nblk = 8 * 7 * B_;   // 448, XCD-swizzled inside kernel
  float* s = P0;
  float* d = P1;
  for (int it = 0; it < 9; ++it) {
    iter_kernel<1><<<nblk, 512, 0, stream>>>(s, aff, d);
    float* t = s; s = d; d = t;
  }
  iter_kernel<0><<<nblk, 512, 0, stream>>>(s, aff, out);
}